// Round 1
// baseline (3361.973 us; speedup 1.0000x reference)
//
#include <hip/hip_runtime.h>
#include <stdint.h>

// BinaryAttention on MI355X (gfx950).  B=64, N=197, C=768, H=12, d=64.
//
// ROUND 12 — DETERMINISM + COALESCING.
// R11's f64 pipeline passed the initial check (1.7e-3) but diverged post-timing
// (4.05e-2). The only call-to-call-variable op was the f64 atomicAdd network
// for s_q/s_k (nondeterministic order across blocks/XCDs); workspace was also
// 90 MB (ws_size overrun risk). This round:
//   * NO atomics: per-(bh,n) row partials -> fixed-order tree reduce (exact
//     same 197-value sets, deterministic order). No ws zero-init needed at all.
//   * PV accumulators stored as int32 (exact: |acc| <= 197*255*127 < 2^23);
//     scale applied in proj. Workspace 90 MB -> 53 MB.
//   * qkv/proj GEMVs: LDS-staged 256x32 weight tiles (coalesced float4 loads,
//     +1 pad) reused across 8 rows/block. Kills the 64-lines-per-wave-load
//     gather that dominated the 87 ms. f64 accumulation order per row is
//     bit-identical to R11 (ascending k, fma).
//   * attn: serial max/sum -> deterministic 256-wide trees (max is order-
//     independent; sum order is FIXED, just different rounding ~1e-15 rel).

#define NT 197
#define HH 12
#define CD 768
#define NB 64
#define MROWS (NB * NT)   // 12608
#define NBH (NB * HH)     // 768
#define RQ 8              // rows per block in the two GEMM kernels
#define YB (MROWS / RQ)   // 1576

// ---- flag-selected flat indexers (flag: 0 = C-order, 1 = F-order) ----
__device__ __forceinline__ size_t idxX(int f, int b, int n, int c) {
  return f ? ((size_t)b + 64u * (size_t)n + 12608u * (size_t)c)
           : ((size_t)(b * NT + n) * CD + c);
}
__device__ __forceinline__ size_t idxW3(int f, int r, int c) {  // qkv_w [2304,768]
  return f ? ((size_t)r + 2304u * (size_t)c) : ((size_t)r * CD + c);
}
__device__ __forceinline__ size_t idxWP(int f, int r, int c) {  // proj_w [768,768]
  return f ? ((size_t)r + 768u * (size_t)c) : ((size_t)r * CD + c);
}
__device__ __forceinline__ size_t idxRT(int f, int i, int h) {  // rel_table [732,12]
  return f ? ((size_t)i + 732u * (size_t)h) : ((size_t)i * HH + h);
}
__device__ __forceinline__ size_t idxRI(int f, int n, int m) {  // rel_index [197,197]
  return f ? ((size_t)n + 197u * (size_t)m) : ((size_t)n * NT + m);
}

// ---- orientation probe (deterministic rel_index: C: ri[1]=729, ri[197]=730) --
__global__ __launch_bounds__(64) void probe_orient(const int* __restrict__ ri,
                                                   int* __restrict__ flag) {
  if (threadIdx.x == 0) {
    const int a = ri[1], b = ri[197];
    flag[0] = (a == 730 && b == 729) ? 1 : 0;
  }
}

// ---------- 1) qkv GEMM, f64 accum, LDS-tiled, 8 rows/block ----------
// grid (9, 1576), block 256. c = blockIdx.x*256 + t; rows row0..row0+7.
__global__ __launch_bounds__(256) void qkv_g(
    const float* __restrict__ x, const float* __restrict__ w,
    uint64_t* __restrict__ qbits, uint64_t* __restrict__ kbits,
    int8_t* __restrict__ vq8, double* __restrict__ qpart,
    double* __restrict__ kpart, const int* __restrict__ flag) {
  __shared__ float wsm[256][33];   // +1 pad: conflict-free column reads
  __shared__ float xsm[RQ][32];

  const int f = flag[0];
  const int t = threadIdx.x;
  const int cBase = blockIdx.x * 256;
  const int c = cBase + t;              // 0..2303
  const int row0 = blockIdx.y * RQ;

  double acc[RQ];
  #pragma unroll
  for (int i = 0; i < RQ; i++) acc[i] = 0.0;

  if (f == 0) {
    for (int k0 = 0; k0 < CD; k0 += 32) {
      // stage w tile [256 c][32 k] via coalesced float4 (8 lines/wave-instr)
      #pragma unroll
      for (int j = 0; j < 8; j++) {
        const int flat = t + 256 * j;          // 0..2047
        const int r = flat >> 3, kq = flat & 7;
        const float4 v4 = *reinterpret_cast<const float4*>(
            w + (size_t)(cBase + r) * CD + k0 + kq * 4);
        wsm[r][kq * 4 + 0] = v4.x; wsm[r][kq * 4 + 1] = v4.y;
        wsm[r][kq * 4 + 2] = v4.z; wsm[r][kq * 4 + 3] = v4.w;
      }
      { // stage x [8 rows][32 k]
        const int r = t >> 5, kk = t & 31;
        const int row = row0 + r, b = row / NT, n = row - b * NT;
        xsm[r][kk] = x[(size_t)(b * NT + n) * CD + k0 + kk];
      }
      __syncthreads();
      for (int kk = 0; kk < 32; kk++) {        // ascending k: same order as R11
        const double wv = (double)wsm[t][kk];
        #pragma unroll
        for (int i = 0; i < RQ; i++) acc[i] += (double)xsm[i][kk] * wv;
      }
      __syncthreads();
    }
  } else {
    // F-order: consecutive out-channels contiguous -> already coalesced
    for (int k = 0; k < CD; k++) {
      const double wv = (double)w[(size_t)c + 2304u * (size_t)k];
      #pragma unroll
      for (int i = 0; i < RQ; i++) {
        const int row = row0 + i, b = row / NT, n = row - b * NT;
        acc[i] += (double)x[(size_t)b + 64u * (size_t)n + 12608u * (size_t)k] * wv;
      }
    }
  }

  // fused quantize epilogue (identical per-row math to R11)
  const int kind = cBase / CD;              // uniform per block (768 % 256 == 0)
  const int h = (c - kind * CD) >> 6;       // uniform per wave
  const int lane = t & 63;                  // == dd
  #pragma unroll
  for (int i = 0; i < RQ; i++) {
    const int row = row0 + i, b = row / NT, n = row - b * NT;
    const int bh = b * HH + h;
    const double a = acc[i];
    if (kind == 2) {
      const double sV = 2.0 / 127.0;
      double vc = fmin(fmax(a, -2.0), 2.0);
      double vq = rint(vc / sV);
      vq = fmin(fmax(vq, -127.0), 127.0);
      vq8[(size_t)(bh * NT + n) * 64 + lane] = (int8_t)(int)vq;
    } else {
      const uint64_t msk = __ballot(a < 0.0);
      double s = fabs(a);
      #pragma unroll
      for (int off = 1; off < 64; off <<= 1) s += __shfl_xor(s, off);
      if (lane == 0) {
        if (kind == 0) { qbits[(size_t)bh * NT + n] = msk; qpart[(size_t)bh * NT + n] = s; }
        else           { kbits[(size_t)bh * NT + n] = msk; kpart[(size_t)bh * NT + n] = s; }
      }
    }
  }
}

// ---------- 1b) deterministic fixed-order reduction of row partials ----------
// grid (768), block 256. sqa[bh] = sum_n qpart[bh*197+n] in a FIXED tree order.
__global__ __launch_bounds__(256) void reduce_s(
    const double* __restrict__ qpart, const double* __restrict__ kpart,
    double* __restrict__ sqa, double* __restrict__ ska) {
  __shared__ double sh[256];
  const int bh = blockIdx.x, t = threadIdx.x;
  sh[t] = (t < NT) ? qpart[(size_t)bh * NT + t] : 0.0;
  __syncthreads();
  for (int s = 128; s > 0; s >>= 1) { if (t < s) sh[t] += sh[t + s]; __syncthreads(); }
  if (t == 0) sqa[bh] = sh[0];
  __syncthreads();
  sh[t] = (t < NT) ? kpart[(size_t)bh * NT + t] : 0.0;
  __syncthreads();
  for (int s = 128; s > 0; s >>= 1) { if (t < s) sh[t] += sh[t + s]; __syncthreads(); }
  if (t == 0) ska[bh] = sh[0];
}

// ---------- 2) attention in f64: one block per (b,h,n) ----------
// grid (197, 768), block 256. Deterministic tree max/sum; int32 PV out.
__global__ __launch_bounds__(256) void attn_f64(
    const uint64_t* __restrict__ qbits, const uint64_t* __restrict__ kbits,
    const int8_t* __restrict__ vq8, const double* __restrict__ sqa,
    const double* __restrict__ ska, const float* __restrict__ rel_table,
    const int* __restrict__ rel_index, int* __restrict__ attn_acc,
    const int* __restrict__ flag) {
  __shared__ double ls[256];
  __shared__ double es[256];
  __shared__ int Pu[NT];

  const int f = flag[0];
  const int n = blockIdx.x;
  const int bh = blockIdx.y;
  const int b = bh / HH, h = bh - b * HH;
  const int t = threadIdx.x;

  const double s_q = sqa[bh] / (double)(NT * 64);
  const double s_k = ska[bh] / (double)(NT * 64);
  const double coef = s_q * s_k * 0.125;
  const uint64_t qb = qbits[(size_t)bh * NT + n];
  const uint64_t* kb = kbits + (size_t)bh * NT;

  double lt;
  if (t < NT) {
    const int dot = 64 - 2 * (int)__popcll(qb ^ kb[t]);
    lt = coef * (double)dot +
         (double)rel_table[idxRT(f, rel_index[idxRI(f, n, t)], h)];
  } else {
    lt = -1e300;
  }
  ls[t] = lt;
  __syncthreads();
  for (int s = 128; s > 0; s >>= 1) {      // exact max (order-independent)
    if (t < s) ls[t] = fmax(ls[t], ls[t + s]);
    __syncthreads();
  }
  const double mx = ls[0];
  const double et = (t < NT) ? exp(lt - mx) : 0.0;
  es[t] = et;
  __syncthreads();
  for (int s = 128; s > 0; s >>= 1) {      // fixed-order sum (deterministic)
    if (t < s) es[t] += es[t + s];
    __syncthreads();
  }
  const double sum = es[0];

  if (t < NT) {
    const double sP = 1.0 / 255.0;
    double P = rint((et / sum) / sP);
    P = fmin(fmax(P, 0.0), 255.0);
    Pu[t] = (int)P;
  }
  __syncthreads();

  // PV: thread dd<64, exact int dot over m (result < 2^23, exact in int32)
  if (t < 64) {
    const int8_t* vb = vq8 + (size_t)bh * NT * 64 + t;
    int acc = 0;
    for (int m = 0; m < NT; m++) acc += Pu[m] * (int)vb[(size_t)m * 64];
    attn_acc[(size_t)(b * NT + n) * CD + h * 64 + t] = acc;
  }
}

// ---------- 3) proj GEMM, f64 accum, LDS-tiled, 8 rows/block ----------
// grid (3, 1576), block 256. out = (sum acc_int*w)*sP*sV + bias, fp32.
__global__ __launch_bounds__(256) void proj_g(
    const int* __restrict__ attn_acc, const float* __restrict__ w,
    const float* __restrict__ bias, float* __restrict__ out,
    const int* __restrict__ flag) {
  __shared__ float wsm[256][33];
  __shared__ int xsi[RQ][32];

  const int f = flag[0];
  const int t = threadIdx.x;
  const int cBase = blockIdx.x * 256;
  const int c = cBase + t;                  // 0..767
  const int row0 = blockIdx.y * RQ;

  double acc[RQ];
  #pragma unroll
  for (int i = 0; i < RQ; i++) acc[i] = 0.0;

  if (f == 0) {
    for (int k0 = 0; k0 < CD; k0 += 32) {
      #pragma unroll
      for (int j = 0; j < 8; j++) {
        const int flat = t + 256 * j;
        const int r = flat >> 3, kq = flat & 7;
        const float4 v4 = *reinterpret_cast<const float4*>(
            w + (size_t)(cBase + r) * CD + k0 + kq * 4);
        wsm[r][kq * 4 + 0] = v4.x; wsm[r][kq * 4 + 1] = v4.y;
        wsm[r][kq * 4 + 2] = v4.z; wsm[r][kq * 4 + 3] = v4.w;
      }
      {
        const int r = t >> 5, kk = t & 31;
        xsi[r][kk] = attn_acc[(size_t)(row0 + r) * CD + k0 + kk];
      }
      __syncthreads();
      for (int kk = 0; kk < 32; kk++) {
        const double wv = (double)wsm[t][kk];
        #pragma unroll
        for (int i = 0; i < RQ; i++) acc[i] += (double)xsi[i][kk] * wv;
      }
      __syncthreads();
    }
  } else {
    for (int k = 0; k < CD; k++) {
      const double wv = (double)w[(size_t)c + 768u * (size_t)k];
      #pragma unroll
      for (int i = 0; i < RQ; i++)
        acc[i] += (double)attn_acc[(size_t)(row0 + i) * CD + k] * wv;
    }
  }

  const double SCALE = (1.0 / 255.0) * (2.0 / 127.0);
  #pragma unroll
  for (int i = 0; i < RQ; i++) {
    const int row = row0 + i, b = row / NT, n = row - b * NT;
    out[idxX(f, b, n, c)] = (float)(acc[i] * SCALE + (double)bias[c]);
  }
}

// ---------------- host launch ----------------
extern "C" void kernel_launch(void* const* d_in, const int* in_sizes, int n_in,
                              void* d_out, int out_size, void* d_ws, size_t ws_size,
                              hipStream_t stream) {
  (void)out_size; (void)ws_size;

  // resolve inputs BY ELEMENT COUNT (all unique; fallback positional)
  const float* x = nullptr;
  const float* qkv_w = nullptr;
  const float* proj_w = nullptr;
  const float* proj_b = nullptr;
  const float* rel_table = nullptr;
  const int* rel_index = nullptr;
  for (int i = 0; i < n_in; i++) {
    switch (in_sizes[i]) {
      case 9682944: x         = (const float*)d_in[i]; break;
      case 1769472: qkv_w     = (const float*)d_in[i]; break;
      case 589824:  proj_w    = (const float*)d_in[i]; break;
      case 768:     proj_b    = (const float*)d_in[i]; break;
      case 8784:    rel_table = (const float*)d_in[i]; break;
      case 38809:   rel_index = (const int*)d_in[i];   break;
      default: break;
    }
  }
  if (!x)         x         = (const float*)d_in[0];
  if (!qkv_w)     qkv_w     = (const float*)d_in[1];
  if (!proj_w)    proj_w    = (const float*)d_in[2];
  if (!proj_b)    proj_b    = (const float*)d_in[3];
  if (!rel_table) rel_table = (const float*)d_in[4];
  if (!rel_index) rel_index = (const int*)d_in[5];
  float* out = (float*)d_out;

  uint8_t* ws = (uint8_t*)d_ws;
  // workspace (~53 MB), every byte written before read each call, no init:
  int*      flag     = (int*)(ws + 0);              //         64
  double*   sqa      = (double*)(ws + 64);          //      6,144
  double*   ska      = (double*)(ws + 6208);        //      6,144
  double*   qpart    = (double*)(ws + 12352);       //  1,210,368
  double*   kpart    = (double*)(ws + 1222720);     //  1,210,368
  uint64_t* qbits    = (uint64_t*)(ws + 2433088);   //  1,210,368
  uint64_t* kbits    = (uint64_t*)(ws + 3643456);   //  1,210,368
  int8_t*   vq8      = (int8_t*)(ws + 4853824);     //  9,682,944
  int*      attn_acc = (int*)(ws + 14536768);       // 38,731,776 -> 53,268,544

  probe_orient<<<1, 64, 0, stream>>>(rel_index, flag);
  qkv_g<<<dim3(9, YB), 256, 0, stream>>>(x, qkv_w, qbits, kbits, vq8,
                                         qpart, kpart, flag);
  reduce_s<<<NBH, 256, 0, stream>>>(qpart, kpart, sqa, ska);
  attn_f64<<<dim3(NT, NBH), 256, 0, stream>>>(qbits, kbits, vq8, sqa, ska,
                                              rel_table, rel_index, attn_acc, flag);
  proj_g<<<dim3(3, YB), 256, 0, stream>>>(attn_acc, proj_w, proj_b, out, flag);
}